// Round 16
// baseline (217.968 us; speedup 1.0000x reference)
//
#include <hip/hip_runtime.h>

// SupProtoConLoss on MI355X — round 16.
// R15 confirmed the fence theory (k_row 152.5->124.5). Decomposition: engine
// 110.5 + tail ~14 + fixed ~55. R9 proved direct-B is 1.43x faster per-wave;
// it lost only to VGPR 244 (full unroll hoisted ~32 loads). R10's depth-2
// starved. Round 16 engine: direct-B with a cyclic 4-slot register pipeline
// under #pragma unroll 4 — bq[(ch+3)&3] indices are per-instance constants
// (no rotation movs), 12 loads outstanding, prefetch distance 3 MFMA phases
// (~930 cyc >= L2 latency), ZERO K-loop barriers. Budget ~230 unified < 256
// -> 2 blocks/CU kept. LDS = As only (~66KB).
// Tail: per-panel done2[p] — 4th block of each panel finalizes its 64 rows
// (parallel, overlapped); 128th finalizer writes out. Serial tail ~3us.

#define NROW 8192
#define DDIM 512
#define NCLS 100
#define PANEL 64
#define JT 256  // cols per j-tile (4 waves x 64)
#define BK 32
#define ZWORDS (2 * NROW + 2 + 128 + 1)  // row_pos|row_neg|gSC[2]|done2[128]|done

typedef float f32x4 __attribute__((ext_vector_type(4)));
typedef short s16x8 __attribute__((ext_vector_type(8)));

#define GLOBAL_AS __attribute__((address_space(1)))
#define LDS_AS __attribute__((address_space(3)))

__device__ __forceinline__ unsigned short f2bf(float x) {
  unsigned int u = __builtin_bit_cast(unsigned int, x);
  u += 0x7FFFu + ((u >> 16) & 1u);  // round-to-nearest-even
  return (unsigned short)(u >> 16);
}

// One wave per row: L2-norm, scale, cast to bf16. Also zeroes the accumulator
// region (row sums + gSC + done2 + done): 9 words per block covers ZWORDS.
__global__ void __launch_bounds__(256) k_prep(
    const float* __restrict__ reps, float* __restrict__ zbase,
    unsigned short* __restrict__ Rb) {
  const int wave = threadIdx.x >> 6;
  const int lane = threadIdx.x & 63;
  const int row = blockIdx.x * 4 + wave;
  if (threadIdx.x < 9) {
    const int zi = blockIdx.x * 9 + threadIdx.x;
    if (zi < ZWORDS) zbase[zi] = 0.0f;
  }
  const float* r = reps + (size_t)row * DDIM;
  float4 v0 = *(const float4*)(r + lane * 4);
  float4 v1 = *(const float4*)(r + 256 + lane * 4);
  float ss = v0.x * v0.x + v0.y * v0.y + v0.z * v0.z + v0.w * v0.w +
             v1.x * v1.x + v1.y * v1.y + v1.z * v1.z + v1.w * v1.w;
#pragma unroll
  for (int m = 1; m < 64; m <<= 1) ss += __shfl_xor(ss, m);
  const float scale = 1.0f / sqrtf(ss);  // norms ~22.6; 1e-8 clamp unreachable
  ushort4 a, b;
  a.x = f2bf(v0.x * scale); a.y = f2bf(v0.y * scale);
  a.z = f2bf(v0.z * scale); a.w = f2bf(v0.w * scale);
  b.x = f2bf(v1.x * scale); b.y = f2bf(v1.y * scale);
  b.z = f2bf(v1.z * scale); b.w = f2bf(v1.w * scale);
  *(ushort4*)(Rb + (size_t)row * DDIM + lane * 4) = a;
  *(ushort4*)(Rb + (size_t)row * DDIM + 256 + lane * 4) = b;
}

// Block = 64-row panel (p = bx>>2) x 2048-col slice (s = bx&3), 4 waves.
// Wave tile per jt: 64 rows x 64 cols = 4a x 4b of 16x16x32 MFMA.
__global__ void __launch_bounds__(256) k_row(
    const unsigned short* __restrict__ Rb, const int* __restrict__ labels,
    float* __restrict__ row_pos, float* __restrict__ row_neg,
    float* __restrict__ gSC, int* __restrict__ done2, int* __restrict__ done,
    float* __restrict__ out) {
  const int bx = blockIdx.x;
  const int p = bx >> 2;   // row panel 0..127
  const int s = bx & 3;    // j slice 0..3 (fixed per XCD under %8 dispatch)
  const int i0 = p * PANEL;
  const int j0s = s * 2048;

  // As chunk-major [ch][row][k-in-chunk] (row stride 64B), 64 KB. No Bs.
  __shared__ __attribute__((aligned(16))) unsigned short As[16][PANEL][BK];
  __shared__ float red[128];
  __shared__ int flag;

  const int tid = threadIdx.x;
  const int lane = tid & 63;
  const int wave = tid >> 6;
  const int quad = lane >> 4, c16 = lane & 15;

  // ---- Stage A panel once, chunk-major: 64 instrs, 16 per wave.
#pragma unroll
  for (int t = 0; t < 16; ++t) {
    const int ii = wave * 16 + t;        // wave-uniform, 0..63
    const int ch = ii >> 2;
    const int rg = (ii & 3) * 16;
    const unsigned short* src =
        Rb + (size_t)(i0 + rg + (lane >> 2)) * DDIM + ch * BK + (lane & 3) * 8;
    __builtin_amdgcn_global_load_lds(
        (GLOBAL_AS void*)const_cast<unsigned short*>(src),
        (LDS_AS void*)(&As[ch][rg][0]), 16, 0, 0);
  }

  // Per-lane row labels and running row sums (live across the whole sweep).
  int li16[16];
  float ps16[16], ns16[16];
#pragma unroll
  for (int a = 0; a < 4; ++a)
#pragma unroll
    for (int r = 0; r < 4; ++r) {
      li16[a * 4 + r] = labels[i0 + a * 16 + quad * 4 + r];
      ps16[a * 4 + r] = 0.0f;
      ns16[a * 4 + r] = 0.0f;
    }

  const float C0 = -5.0f + 1e-7f;  // s = 5g - 5 + 1e-7 (static shift S=10)

  __syncthreads();  // A staging visible; the ONLY pre-epilogue barrier

  for (int jt = 0; jt < 8; ++jt) {
    const int j0 = j0s + jt * JT;
    int lj[4], gj[4];
    const unsigned short* bp[4];  // per-b base: row gj[b], this lane's k8
#pragma unroll
    for (int b = 0; b < 4; ++b) {
      gj[b] = j0 + wave * 64 + b * 16 + c16;
      lj[b] = labels[gj[b]];
      bp[b] = Rb + (size_t)gj[b] * DDIM + quad * 8;
    }

    f32x4 acc[4][4];
#pragma unroll
    for (int a = 0; a < 4; ++a)
#pragma unroll
      for (int b = 0; b < 4; ++b) acc[a][b] = (f32x4)0.0f;

    // Cyclic 4-slot B pipeline: slots ch&3; loads issued 3 iterations ahead
    // (12 outstanding). unroll 4 makes all slot indices instance-constants.
    s16x8 bq[4][4];
#pragma unroll
    for (int c = 0; c < 3; ++c)
#pragma unroll
      for (int b = 0; b < 4; ++b)
        bq[c][b] = *(const s16x8*)(bp[b] + c * BK);

#pragma unroll 4
    for (int ch = 0; ch < 16; ++ch) {
      s16x8 af[4];
#pragma unroll
      for (int a = 0; a < 4; ++a)
        af[a] = *(const s16x8*)(&As[ch][a * 16 + c16][quad * 8]);
      if (ch < 13) {
#pragma unroll
        for (int b = 0; b < 4; ++b)
          bq[(ch + 3) & 3][b] = *(const s16x8*)(bp[b] + (ch + 3) * BK);
      }
#pragma unroll
      for (int a = 0; a < 4; ++a)
#pragma unroll
        for (int b = 0; b < 4; ++b)
          acc[a][b] = __builtin_amdgcn_mfma_f32_16x16x32_bf16(
              af[a], bq[ch & 3][b], acc[a][b], 0, 0, 0);
    }

    // Fold this j-tile into register row sums (no atomics).
#pragma unroll
    for (int a = 0; a < 4; ++a) {
#pragma unroll
      for (int r = 0; r < 4; ++r) {
        const int gi = i0 + a * 16 + quad * 4 + r;
        const int li = li16[a * 4 + r];
        float ps = 0.0f, ns = 0.0f;
#pragma unroll
        for (int b = 0; b < 4; ++b) {
          const float g = acc[a][b][r];
          const float sv = fmaf(g, 5.0f, C0);
          const float ev = __expf(sv);
          const bool same = (li == lj[b]);
          ps += (same && gi != gj[b]) ? sv : 0.0f;
          ns += same ? 0.0f : ev;
        }
        ps16[a * 4 + r] += ps;
        ns16[a * 4 + r] += ns;
      }
    }
  }

  // ---- Block epilogue: reduce per-lane sums -> 64 rows, 2 atomics each.
  float* rp = red;       // 64 floats
  float* rn = red + 64;  // 64 floats
  if (tid < 128) red[tid] = 0.0f;
  __syncthreads();
#pragma unroll
  for (int a = 0; a < 4; ++a) {
#pragma unroll
    for (int r = 0; r < 4; ++r) {
      float ps = ps16[a * 4 + r], ns = ns16[a * 4 + r];
#pragma unroll
      for (int m = 1; m < 16; m <<= 1) {  // reduce across the 16 c16 lanes
        ps += __shfl_xor(ps, m);
        ns += __shfl_xor(ns, m);
      }
      if (c16 == 0) {
        atomicAdd(&rp[a * 16 + quad * 4 + r], ps);
        atomicAdd(&rn[a * 16 + quad * 4 + r], ns);
      }
    }
  }
  __syncthreads();
  if (tid < 64) {
    atomicAdd(&row_pos[i0 + tid], rp[tid]);   // device-scope, 4/address
    atomicAdd(&row_neg[i0 + tid], rn[tid]);
  }

  // ---- Per-panel finalize: 4th finisher of panel p handles its 64 rows.
  // No release fence (R15): the barrier below drains vmcnt, so the row
  // atomics are at the device coherence point before done2 is bumped.
  __syncthreads();
  if (tid == 0) flag = (atomicAdd(&done2[p], 1) == 3) ? 1 : 0;
  __syncthreads();
  if (flag == 0) return;

  // Label histogram (read-only input -> plain loads fine). As is dead.
  int* hcnt = (int*)&As[0][0][0];
  if (tid < NCLS) hcnt[tid] = 0;
  __syncthreads();
  for (int i = tid; i < NROW; i += 256) atomicAdd(&hcnt[labels[i]], 1);
  __syncthreads();
  float lsum = 0.0f, lcnt = 0.0f;
  if (tid < 64) {
    // Atomic reads: one pair per thread, fully parallel (device-coherent).
    const float rpv = atomicAdd(&row_pos[i0 + tid], 0.0f);
    const float rnv = atomicAdd(&row_neg[i0 + tid], 0.0f);
    const float c = (float)(hcnt[labels[i0 + tid]] - 1);
    const float loss = -(rpv / (c + 1e-8f)) + __logf(rnv + 1e-8f);
    if (loss > 0.0f) { lsum = loss; lcnt = 1.0f; }
#pragma unroll
    for (int m = 1; m < 64; m <<= 1) {
      lsum += __shfl_xor(lsum, m);
      lcnt += __shfl_xor(lcnt, m);
    }
    if (tid == 0) { atomicAdd(&gSC[0], lsum); atomicAdd(&gSC[1], lcnt); }
  }
  __syncthreads();  // drains tid0's gSC adds to the coherence point
  if (tid == 0 && atomicAdd(done, 1) == 127) {
    // All 128 finalizers bumped done AFTER their gSC adds completed.
    const float S = atomicAdd(&gSC[0], 0.0f);
    const float C = atomicAdd(&gSC[1], 0.0f);
    out[0] = S / (C + 1e-8f);
  }
}

extern "C" void kernel_launch(void* const* d_in, const int* in_sizes, int n_in,
                              void* d_out, int out_size, void* d_ws, size_t ws_size,
                              hipStream_t stream) {
  const float* reps = (const float*)d_in[0];
  const int* labels = (const int*)d_in[1];
  float* out = (float*)d_out;
  char* ws = (char*)d_ws;
  // ws: Rb (8 MiB) | row_pos[8192] row_neg[8192] gSC[2] done2[128] done[1]
  unsigned short* Rb = (unsigned short*)ws;
  float* row_pos = (float*)(ws + (size_t)NROW * DDIM * 2);
  float* row_neg = row_pos + NROW;
  float* gSC = row_neg + NROW;
  int* done2 = (int*)(gSC + 2);
  int* done = done2 + 128;

  k_prep<<<NROW / 4, 256, 0, stream>>>(reps, row_pos, Rb);
  k_row<<<512, 256, 0, stream>>>(Rb, labels, row_pos, row_neg, gSC, done2,
                                 done, out);
  (void)in_sizes; (void)n_in; (void)out_size; (void)ws_size;
}